// Round 1
// baseline (200.685 us; speedup 1.0000x reference)
//
#include <hip/hip_runtime.h>

// DiffDMC forward, D=128.
// Padded grid g: 130^3, pad value = iso+1 = 1.0; padded deform = 0.
// Cells: C = 129 per axis. Outputs (flat float32, concatenated):
//   verts   [0,        6440067)   : 129^3 x 3
//   vmask   [6440067,  8586756)   : 129^3
//   quads   [8586756,  33949188)  : 3*129*128*128 quads x 4
//   qmask   [33949188, 40289796)  : 3*129*128*128
#define DRES 128
#define CC   129
#define NCELL (CC*CC*CC)               // 2146689
#define NSEG  (CC*(CC-1)*(CC-1))       // 2113536
#define NQ    (3*NSEG)                 // 6340608
#define VERTS_OFF   0
#define VMASK_OFF   ((size_t)NCELL*3)            // 6440067
#define QUADS_OFF   (VMASK_OFF + (size_t)NCELL)  // 8586756 (x4 bytes -> 16B aligned)
#define QMASK_OFF   (QUADS_OFF + (size_t)NQ*4)   // 33949188

__device__ __forceinline__ float gpad(const float* __restrict__ g, int x, int y, int z) {
    // x,y,z are PADDED coords in [0,130); interior maps to grid[x-1,y-1,z-1]
    if (((unsigned)(x - 1) < (unsigned)DRES) &&
        ((unsigned)(y - 1) < (unsigned)DRES) &&
        ((unsigned)(z - 1) < (unsigned)DRES)) {
        return g[((size_t)(x - 1) * DRES + (y - 1)) * DRES + (z - 1)];
    }
    return 1.0f;  // iso + 1
}

__global__ void __launch_bounds__(256) cells_kernel(
    const float* __restrict__ grid, const float* __restrict__ deform,
    float* __restrict__ out)
{
    int id = blockIdx.x * blockDim.x + threadIdx.x;
    if (id >= NCELL) return;
    int k = id % CC;
    int t = id / CC;
    int j = t % CC;
    int i = t / CC;

    const int cx[8] = {0,1,1,0,0,1,1,0};
    const int cy[8] = {0,0,1,1,0,0,1,1};
    const int cz[8] = {0,0,0,0,1,1,1,1};

    float v[8], px[8], py[8], pz[8];
    #pragma unroll
    for (int c = 0; c < 8; ++c) {
        int x = i + cx[c], y = j + cy[c], z = k + cz[c];
        bool inside = ((unsigned)(x - 1) < (unsigned)DRES) &&
                      ((unsigned)(y - 1) < (unsigned)DRES) &&
                      ((unsigned)(z - 1) < (unsigned)DRES);
        float gv = 1.0f, dx = 0.f, dy = 0.f, dz = 0.f;
        if (inside) {
            size_t off = ((size_t)(x - 1) * DRES + (y - 1)) * DRES + (z - 1);
            gv = grid[off];
            const float* dp = deform + off * 3;
            dx = dp[0]; dy = dp[1]; dz = dp[2];
        }
        v[c]  = gv;
        px[c] = (float)x + dx;
        py[c] = (float)y + dy;
        pz[c] = (float)z + dz;
    }

    const int ea[12] = {0,1,2,3,4,5,6,7,0,1,2,3};
    const int eb[12] = {1,2,3,0,5,6,7,4,4,5,6,7};
    float sx = 0.f, sy = 0.f, sz = 0.f, cnt = 0.f;
    #pragma unroll
    for (int e = 0; e < 12; ++e) {
        float va = v[ea[e]], vb = v[eb[e]];
        float m = ((va < 0.f) != (vb < 0.f)) ? 1.0f : 0.0f;
        float denom = vb - va;
        denom = (denom == 0.f) ? 1.0f : denom;
        float tt = (0.f - va) / denom;
        tt = fminf(fmaxf(tt, 0.f), 1.f);
        sx += m * (px[ea[e]] + tt * (px[eb[e]] - px[ea[e]]));
        sy += m * (py[ea[e]] + tt * (py[eb[e]] - py[ea[e]]));
        sz += m * (pz[ea[e]] + tt * (pz[eb[e]] - pz[ea[e]]));
        cnt += m;
    }

    bool active = cnt > 0.f;
    float den = fmaxf(cnt, 1.f);
    float ox = ((sx / den) - 1.f) / 127.f;
    float oy = ((sy / den) - 1.f) / 127.f;
    float oz = ((sz / den) - 1.f) / 127.f;
    if (!active) { ox = 0.f; oy = 0.f; oz = 0.f; }

    out[VERTS_OFF + (size_t)id * 3 + 0] = ox;
    out[VERTS_OFF + (size_t)id * 3 + 1] = oy;
    out[VERTS_OFF + (size_t)id * 3 + 2] = oz;
    out[VMASK_OFF + (size_t)id]         = active ? 1.f : 0.f;
}

__global__ void __launch_bounds__(256) quads_kernel(
    const float* __restrict__ grid, float* __restrict__ out)
{
    int id = blockIdx.x * blockDim.x + threadIdx.x;
    if (id >= NQ) return;
    int seg = id / NSEG;
    int r   = id - seg * NSEG;

    int i0, i1, i2, i3;
    int ax, ay, az, bx, by, bz;  // padded coords of the two sign-test samples
    if (seg == 0) {
        // (a in [0,129), b,c in [0,128)); edge along axis 0
        int c = r % 128; int t = r / 128; int b = t % 128; int a = t / 128;
        i0 = (a * CC + b) * CC + c;
        i1 = (a * CC + (b + 1)) * CC + c;
        i2 = (a * CC + (b + 1)) * CC + (c + 1);
        i3 = (a * CC + b) * CC + (c + 1);
        ax = a;     ay = b + 1; az = c + 1;
        bx = a + 1; by = b + 1; bz = c + 1;
    } else if (seg == 1) {
        // (a,c in [0,128), b in [0,129)); edge along axis 1
        int c = r % 128; int t = r / 128; int b = t % 129; int a = t / 129;
        i0 = (a * CC + b) * CC + c;
        i1 = ((a + 1) * CC + b) * CC + c;
        i2 = ((a + 1) * CC + b) * CC + (c + 1);
        i3 = (a * CC + b) * CC + (c + 1);
        ax = a + 1; ay = b;     az = c + 1;
        bx = a + 1; by = b + 1; bz = c + 1;
    } else {
        // (a,b in [0,128), c in [0,129)); edge along axis 2
        int c = r % 129; int t = r / 129; int b = t % 128; int a = t / 128;
        i0 = (a * CC + b) * CC + c;
        i1 = ((a + 1) * CC + b) * CC + c;
        i2 = ((a + 1) * CC + (b + 1)) * CC + c;
        i3 = (a * CC + (b + 1)) * CC + c;
        ax = a + 1; ay = b + 1; az = c;
        bx = a + 1; by = b + 1; bz = c + 1;
    }

    bool sa = gpad(grid, ax, ay, az) < 0.f;
    bool sb = gpad(grid, bx, by, bz) < 0.f;

    float4 q = make_float4((float)i0, (float)i1, (float)i2, (float)i3);
    reinterpret_cast<float4*>(out + QUADS_OFF)[id] = q;
    out[QMASK_OFF + (size_t)id] = (sa != sb) ? 1.f : 0.f;
}

extern "C" void kernel_launch(void* const* d_in, const int* in_sizes, int n_in,
                              void* d_out, int out_size, void* d_ws, size_t ws_size,
                              hipStream_t stream) {
    const float* grid   = (const float*)d_in[0];
    const float* deform = (const float*)d_in[1];
    float* out = (float*)d_out;

    cells_kernel<<<(NCELL + 255) / 256, 256, 0, stream>>>(grid, deform, out);
    quads_kernel<<<(NQ + 255) / 256, 256, 0, stream>>>(grid, out);
}

// Round 5
// 197.562 us; speedup vs baseline: 1.0158x; 1.0158x over previous
//
#include <hip/hip_runtime.h>

// DiffDMC forward, D=128 — fused single-dispatch version.
// Threads [0, NCELL)        : dual-vertex path (one cell each)
// Threads [NCELL, NCELL+NQ) : quad-index/mask path (one quad each)
//
// Output layout (flat float32):
//   verts   [0,        6440067)   : 129^3 x 3
//   vmask   [6440067,  8586756)   : 129^3
//   quads   [8586756,  33949188)  : 3*129*128*128 x 4   (16B-aligned base)
//   qmask   [33949188, 40289796)  : 3*129*128*128
#define DRES 128
#define CC   129
#define NCELL (CC*CC*CC)               // 2146689
#define NSEG  (CC*(CC-1)*(CC-1))       // 2113536
#define NQ    (3*NSEG)                 // 6340608
#define NTOT  (NCELL + NQ)             // 8487297
#define VERTS_OFF   0
#define VMASK_OFF   ((size_t)NCELL*3)            // 6440067
#define QUADS_OFF   (VMASK_OFF + (size_t)NCELL)  // 8586756
#define QMASK_OFF   (QUADS_OFF + (size_t)NQ*4)   // 33949188

typedef float f32x4 __attribute__((ext_vector_type(4)));

__device__ __forceinline__ float gpad(const float* __restrict__ g, int x, int y, int z) {
    // x,y,z are PADDED coords in [0,130); interior maps to grid[x-1,y-1,z-1]
    if (((unsigned)(x - 1) < (unsigned)DRES) &&
        ((unsigned)(y - 1) < (unsigned)DRES) &&
        ((unsigned)(z - 1) < (unsigned)DRES)) {
        return g[((size_t)(x - 1) * DRES + (y - 1)) * DRES + (z - 1)];
    }
    return 1.0f;  // iso + 1
}

__global__ void __launch_bounds__(256) dmc_fused_kernel(
    const float* __restrict__ grid, const float* __restrict__ deform,
    float* __restrict__ out)
{
    int gid = blockIdx.x * blockDim.x + threadIdx.x;

    if (gid < NCELL) {
        // ---------------- cells path ----------------
        int id = gid;
        int k = id % CC;
        int t = id / CC;
        int j = t % CC;
        int i = t / CC;

        const int cx[8] = {0,1,1,0,0,1,1,0};
        const int cy[8] = {0,0,1,1,0,0,1,1};
        const int cz[8] = {0,0,0,0,1,1,1,1};

        float v[8], px[8], py[8], pz[8];
        #pragma unroll
        for (int c = 0; c < 8; ++c) {
            int x = i + cx[c], y = j + cy[c], z = k + cz[c];
            bool inside = ((unsigned)(x - 1) < (unsigned)DRES) &&
                          ((unsigned)(y - 1) < (unsigned)DRES) &&
                          ((unsigned)(z - 1) < (unsigned)DRES);
            float gv = 1.0f, dx = 0.f, dy = 0.f, dz = 0.f;
            if (inside) {
                size_t off = ((size_t)(x - 1) * DRES + (y - 1)) * DRES + (z - 1);
                gv = grid[off];
                const float* dp = deform + off * 3;
                dx = dp[0]; dy = dp[1]; dz = dp[2];
            }
            v[c]  = gv;
            px[c] = (float)x + dx;
            py[c] = (float)y + dy;
            pz[c] = (float)z + dz;
        }

        const int ea[12] = {0,1,2,3,4,5,6,7,0,1,2,3};
        const int eb[12] = {1,2,3,0,5,6,7,4,4,5,6,7};
        float sx = 0.f, sy = 0.f, sz = 0.f, cnt = 0.f;
        #pragma unroll
        for (int e = 0; e < 12; ++e) {
            float va = v[ea[e]], vb = v[eb[e]];
            float m = ((va < 0.f) != (vb < 0.f)) ? 1.0f : 0.0f;
            float denom = vb - va;
            denom = (denom == 0.f) ? 1.0f : denom;
            // fast reciprocal instead of full-precision fdiv (~1 ulp on t)
            float tt = (0.f - va) * __builtin_amdgcn_rcpf(denom);
            tt = fminf(fmaxf(tt, 0.f), 1.f);
            sx += m * (px[ea[e]] + tt * (px[eb[e]] - px[ea[e]]));
            sy += m * (py[ea[e]] + tt * (py[eb[e]] - py[ea[e]]));
            sz += m * (pz[ea[e]] + tt * (pz[eb[e]] - pz[ea[e]]));
            cnt += m;
        }

        bool active = cnt > 0.f;
        float den = fmaxf(cnt, 1.f);
        float rden = __builtin_amdgcn_rcpf(den);   // den in {1..12}, exact for 1,2,4,8
        float ox = ((sx * rden) - 1.f) / 127.f;
        float oy = ((sy * rden) - 1.f) / 127.f;
        float oz = ((sz * rden) - 1.f) / 127.f;
        if (!active) { ox = 0.f; oy = 0.f; oz = 0.f; }

        __builtin_nontemporal_store(ox, out + VERTS_OFF + (size_t)id * 3 + 0);
        __builtin_nontemporal_store(oy, out + VERTS_OFF + (size_t)id * 3 + 1);
        __builtin_nontemporal_store(oz, out + VERTS_OFF + (size_t)id * 3 + 2);
        __builtin_nontemporal_store(active ? 1.f : 0.f, out + VMASK_OFF + (size_t)id);

    } else if (gid < NTOT) {
        // ---------------- quads path ----------------
        int id = gid - NCELL;
        int seg = id / NSEG;
        int r   = id - seg * NSEG;

        int i0, i1, i2, i3;
        int ax, ay, az, bx, by, bz;  // padded coords of the two sign-test samples
        if (seg == 0) {
            int c = r % 128; int t = r / 128; int b = t % 128; int a = t / 128;
            i0 = (a * CC + b) * CC + c;
            i1 = (a * CC + (b + 1)) * CC + c;
            i2 = (a * CC + (b + 1)) * CC + (c + 1);
            i3 = (a * CC + b) * CC + (c + 1);
            ax = a;     ay = b + 1; az = c + 1;
            bx = a + 1; by = b + 1; bz = c + 1;
        } else if (seg == 1) {
            int c = r % 128; int t = r / 128; int b = t % 129; int a = t / 129;
            i0 = (a * CC + b) * CC + c;
            i1 = ((a + 1) * CC + b) * CC + c;
            i2 = ((a + 1) * CC + b) * CC + (c + 1);
            i3 = (a * CC + b) * CC + (c + 1);
            ax = a + 1; ay = b;     az = c + 1;
            bx = a + 1; by = b + 1; bz = c + 1;
        } else {
            int c = r % 129; int t = r / 129; int b = t % 128; int a = t / 128;
            i0 = (a * CC + b) * CC + c;
            i1 = ((a + 1) * CC + b) * CC + c;
            i2 = ((a + 1) * CC + (b + 1)) * CC + c;
            i3 = (a * CC + (b + 1)) * CC + c;
            ax = a + 1; ay = b + 1; az = c;
            bx = a + 1; by = b + 1; bz = c + 1;
        }

        bool sa = gpad(grid, ax, ay, az) < 0.f;
        bool sb = gpad(grid, bx, by, bz) < 0.f;

        f32x4 q = { (float)i0, (float)i1, (float)i2, (float)i3 };
        __builtin_nontemporal_store(q, reinterpret_cast<f32x4*>(out + QUADS_OFF) + id);
        __builtin_nontemporal_store((sa != sb) ? 1.f : 0.f, out + QMASK_OFF + (size_t)id);
    }
}

extern "C" void kernel_launch(void* const* d_in, const int* in_sizes, int n_in,
                              void* d_out, int out_size, void* d_ws, size_t ws_size,
                              hipStream_t stream) {
    const float* grid   = (const float*)d_in[0];
    const float* deform = (const float*)d_in[1];
    float* out = (float*)d_out;

    dmc_fused_kernel<<<(NTOT + 255) / 256, 256, 0, stream>>>(grid, deform, out);
}